// Round 2
// baseline (24188.213 us; speedup 1.0000x reference)
//
#include <hip/hip_runtime.h>
#include <hip/hip_bf16.h>
#include <math.h>

#define S_LEN 512
#define BATCH 32
#define HID   512
#define G4    2048   // 4*H
#define DIM   300
#define NHEAD 8
#define HDIM  128
#define CH    64     // timesteps per xg chunk
#define NCH   8

typedef __hip_bfloat16 bf16;

// ---------------- workspace layout (float offsets) ----------------
// xgc:    [2 dir][64 slot][2048 n][32 b]          8,388,608 f
// hcat0:  [32 b][512 s][1024]                    16,777,216 f
// hcat1:  [32 b][512 s][1024]                    16,777,216 f  (h0 [16384][300] aliases its start)
// Wp:     [3072 n][1024 k]                        3,145,728 f
// pb:     [3072]                                      3,072 f
// cT:     [2 dir][512 u][32 b]                       32,768 f
// hT:     [2 parity][2 dir][512 k][32 b]             65,536 f
// pooled: [32 b][1024]                               32,768 f
// QKV bf16 (3 * 16,777,216 elems = 25,165,824 float-slots) aliases [xgc + hcat0] exactly.
#define OFF_XGC   0ull
#define OFF_HCAT0 8388608ull
#define OFF_HCAT1 25165824ull
#define OFF_H0    25165824ull
#define OFF_WP    41943040ull
#define OFF_PB    45088768ull
#define OFF_CT    45091840ull
#define OFF_HT    45124608ull
#define OFF_POOL  45190144ull
// total: 45,222,912 floats = 180.9 MB

// ---------------- embedding gather ----------------
__global__ void k_embed(const int* __restrict__ x, const float* __restrict__ emb,
                        float* __restrict__ h0)
{
    int p = blockIdx.x;                 // p = b*512 + s
    int row = x[p];
    const float* src = emb + (size_t)row * DIM;
    float* dst = h0 + (size_t)p * DIM;
    for (int d = threadIdx.x; d < DIM; d += blockDim.x) dst[d] = src[d];
}

// ---------------- chunk input-projection GEMM ----------------
// Per chunk c (c64 = c*64): for dir in {0,1}: rows m = slot*32+b  (slot 0..63, b 0..31)
//   source token s = dir ? 511-c64-slot : c64+slot
//   xgc[((dir*64+slot)*2048 + n)*32 + b] = A[b][s][:] . W[n][:] + bih[n] + bhh[n]
__global__ __launch_bounds__(256) void k_xgc(const float* __restrict__ A, int lda,
    const float* __restrict__ Wf, const float* __restrict__ Wb,
    const float* __restrict__ bihf, const float* __restrict__ bhhf,
    const float* __restrict__ bihb, const float* __restrict__ bhhb,
    float* __restrict__ xgc, int K, int c64)
{
    __shared__ float As[8][128];
    __shared__ float Bs[8][128];
    int tid = threadIdx.x;
    int dir = blockIdx.z;
    int m0 = blockIdx.y * 128, n0 = blockIdx.x * 128;
    const float* W  = dir ? Wb : Wf;
    const float* b1 = dir ? bihb : bihf;
    const float* b2 = dir ? bhhb : bhhf;
    int tx = tid & 15, ty = tid >> 4;

    float acc[8][8];
#pragma unroll
    for (int i = 0; i < 8; i++)
#pragma unroll
        for (int j = 0; j < 8; j++) acc[i][j] = 0.f;

    for (int k0 = 0; k0 < K; k0 += 8) {
#pragma unroll
        for (int e4 = 0; e4 < 4; e4++) {
            int e = tid * 4 + e4;
            int kl = e & 7, ml = e >> 3;
            int kk = k0 + kl;
            int m = m0 + ml;
            int slot = m >> 5, bb = m & 31;
            int s = dir ? (S_LEN - 1 - c64 - slot) : (c64 + slot);
            As[kl][ml] = (kk < K) ? A[((size_t)bb * S_LEN + s) * lda + kk] : 0.f;
            Bs[kl][ml] = (kk < K) ? W[(size_t)(n0 + ml) * K + kk] : 0.f;
        }
        __syncthreads();
#pragma unroll
        for (int k = 0; k < 8; k++) {
            float a[8], b[8];
#pragma unroll
            for (int i = 0; i < 8; i++) a[i] = As[k][ty + 16 * i];
#pragma unroll
            for (int j = 0; j < 8; j++) b[j] = Bs[k][tx + 16 * j];
#pragma unroll
            for (int i = 0; i < 8; i++)
#pragma unroll
                for (int j = 0; j < 8; j++) acc[i][j] += a[i] * b[j];
        }
        __syncthreads();
    }

#pragma unroll
    for (int i = 0; i < 8; i++) {
        int m = m0 + ty + 16 * i;
        int slot = m >> 5, bb = m & 31;
#pragma unroll
        for (int j = 0; j < 8; j++) {
            int n = n0 + tx + 16 * j;
            xgc[(((size_t)dir * CH + slot) * G4 + n) * BATCH + bb] =
                acc[i][j] + b1[n] + b2[n];
        }
    }
}

// ---------------- one LSTM step (both directions), coalesced ----------------
// grid 256: wg = dir*128 + ublk (4 hidden units). 256 threads = 32 b x 4 uu x 2 khalf.
// hT double-buffered by step parity (cross-WG read/write race avoidance).
__global__ __launch_bounds__(256) void k_step(const float* __restrict__ xgc,
    const float* __restrict__ Whh_f, const float* __restrict__ Whh_b,
    float* __restrict__ hT, float* __restrict__ cT, float* __restrict__ hcat, int tt)
{
    int wg = blockIdx.x;
    int dir = wg >> 7, ublk = wg & 127;
    int u0 = ublk * 4;
    const float* Whh = dir ? Whh_b : Whh_f;
    int s_cur = dir ? (S_LEN - 1 - tt) : tt;
    int slot = tt & (CH - 1);
    int tid = threadIdx.x;
    int b  = tid & 31;
    int uu = (tid >> 5) & 3;
    int kh = tid >> 7;
    int u = u0 + uu;

    float acc0 = 0.f, acc1 = 0.f, acc2 = 0.f, acc3 = 0.f;
    if (tt > 0) {
        const float* hTd = hT + ((size_t)((tt & 1) ^ 1) * 2 + dir) * 16384;
        int k0 = kh * 256;
        const float4* w0 = (const float4*)(Whh + ((size_t)(0 * HID + u)) * HID + k0);
        const float4* w1 = (const float4*)(Whh + ((size_t)(1 * HID + u)) * HID + k0);
        const float4* w2 = (const float4*)(Whh + ((size_t)(2 * HID + u)) * HID + k0);
        const float4* w3 = (const float4*)(Whh + ((size_t)(3 * HID + u)) * HID + k0);
        const float* hb = hTd + (size_t)k0 * 32 + b;
#pragma unroll 8
        for (int k4 = 0; k4 < 64; k4++) {
            float h0v = hb[(k4 * 4 + 0) * 32];
            float h1v = hb[(k4 * 4 + 1) * 32];
            float h2v = hb[(k4 * 4 + 2) * 32];
            float h3v = hb[(k4 * 4 + 3) * 32];
            float4 a0 = w0[k4], a1 = w1[k4], a2 = w2[k4], a3 = w3[k4];
            acc0 += a0.x * h0v + a0.y * h1v + a0.z * h2v + a0.w * h3v;
            acc1 += a1.x * h0v + a1.y * h1v + a1.z * h2v + a1.w * h3v;
            acc2 += a2.x * h0v + a2.y * h1v + a2.z * h2v + a2.w * h3v;
            acc3 += a3.x * h0v + a3.y * h1v + a3.z * h2v + a3.w * h3v;
        }
    }

    __shared__ float red[4][4][32];
    if (kh) {
        red[uu][0][b] = acc0; red[uu][1][b] = acc1;
        red[uu][2][b] = acc2; red[uu][3][b] = acc3;
    }
    __syncthreads();
    if (!kh) {
        size_t xbase = (((size_t)dir * CH + slot) * G4) * BATCH;
        float gi = acc0 + red[uu][0][b] + xgc[xbase + (size_t)(0 * HID + u) * BATCH + b];
        float gf = acc1 + red[uu][1][b] + xgc[xbase + (size_t)(1 * HID + u) * BATCH + b];
        float gg = acc2 + red[uu][2][b] + xgc[xbase + (size_t)(2 * HID + u) * BATCH + b];
        float go = acc3 + red[uu][3][b] + xgc[xbase + (size_t)(3 * HID + u) * BATCH + b];
        size_t ci = ((size_t)dir * HID + u) * 32 + b;
        float cp = (tt > 0) ? cT[ci] : 0.f;
        float si = 1.f / (1.f + expf(-gi));
        float sf = 1.f / (1.f + expf(-gf));
        float so = 1.f / (1.f + expf(-go));
        float cn = sf * cp + si * tanhf(gg);
        float hn = so * tanhf(cn);
        cT[ci] = cn;
        hT[((size_t)(tt & 1) * 2 + dir) * 16384 + (size_t)u * 32 + b] = hn;
        hcat[((size_t)b * S_LEN + s_cur) * 1024 + dir * HID + u] = hn;
    }
}

// ---------------- pack Wq/Wk/Wv -> Wp[3072][1024] + packed bias ----------------
__global__ void k_pack(const float* __restrict__ Wq, const float* __restrict__ Wk,
                       const float* __restrict__ Wv, const float* __restrict__ bq,
                       const float* __restrict__ bk, const float* __restrict__ bv,
                       float* __restrict__ Wp, float* __restrict__ pb)
{
    size_t i = (size_t)blockIdx.x * 256 + threadIdx.x;
    if (i < 3ull * 1024 * 1024) {
        int tt = (int)(i >> 20);
        int w  = (int)(i & 1048575);
        int n  = w >> 10;      // h*128+e
        int d  = w & 1023;
        int hh = n >> 7, e = n & 127;
        const float* W = (tt == 0) ? Wq : (tt == 1 ? Wk : Wv);
        Wp[i] = W[((size_t)hh * 1024 + d) * 128 + e];
    }
    if (i < 3072) {
        int tt = (int)(i >> 10), w = (int)(i & 1023);
        const float* bb = (tt == 0) ? bq : (tt == 1 ? bk : bv);
        pb[i] = bb[w];
    }
}

// ---------------- QKV GEMM (f32 compute, bf16 out) ----------------
// A = hcat1 rows m=b*512+s (lda=1024); W = Wp[3072][1024];
// out: Q/K/V bf16 [b*8+h][512 s][128 e] per tensor
__global__ __launch_bounds__(256) void k_qkv(const float* __restrict__ A,
    const float* __restrict__ Wp, const float* __restrict__ pb,
    bf16* __restrict__ Qout)
{
    __shared__ float As[8][128];
    __shared__ float Bs[8][128];
    int tid = threadIdx.x;
    int m0 = blockIdx.y * 128, n0 = blockIdx.x * 128;
    int tx = tid & 15, ty = tid >> 4;

    float acc[8][8];
#pragma unroll
    for (int i = 0; i < 8; i++)
#pragma unroll
        for (int j = 0; j < 8; j++) acc[i][j] = 0.f;

    for (int k0 = 0; k0 < 1024; k0 += 8) {
#pragma unroll
        for (int e4 = 0; e4 < 4; e4++) {
            int e = tid * 4 + e4;
            int kl = e & 7, ml = e >> 3;
            int kk = k0 + kl;
            As[kl][ml] = A[(size_t)(m0 + ml) * 1024 + kk];
            Bs[kl][ml] = Wp[(size_t)(n0 + ml) * 1024 + kk];
        }
        __syncthreads();
#pragma unroll
        for (int k = 0; k < 8; k++) {
            float a[8], b[8];
#pragma unroll
            for (int i = 0; i < 8; i++) a[i] = As[k][ty + 16 * i];
#pragma unroll
            for (int j = 0; j < 8; j++) b[j] = Bs[k][tx + 16 * j];
#pragma unroll
            for (int i = 0; i < 8; i++)
#pragma unroll
                for (int j = 0; j < 8; j++) acc[i][j] += a[i] * b[j];
        }
        __syncthreads();
    }

#pragma unroll
    for (int i = 0; i < 8; i++) {
        int m = m0 + ty + 16 * i;
        int b = m >> 9, s = m & 511;
#pragma unroll
        for (int j = 0; j < 8; j++) {
            int n = n0 + tx + 16 * j;
            int tt = n >> 10, w = n & 1023, hh = w >> 7, e = w & 127;
            float v = acc[i][j] + pb[n];
            Qout[(size_t)tt * 16777216ull +
                 ((size_t)(b * NHEAD + hh) * S_LEN + s) * HDIM + e] = __float2bfloat16(v);
        }
    }
}

// ---------------- attention: softmax column-weights -> pooled ----------------
// one WG per (b,h).  pooled[b][h*128+e] = (1/512) * sum_t (sum_s P(s,t)) * V[t][e]
__global__ __launch_bounds__(256) void k_attn(const bf16* __restrict__ Q,
    const bf16* __restrict__ K, const bf16* __restrict__ V,
    float* __restrict__ pooled)
{
    int bh = blockIdx.x;
    int b = bh >> 3, h = bh & 7;
    const bf16* Qb = Q + (size_t)bh * S_LEN * HDIM;
    const bf16* Kb = K + (size_t)bh * S_LEN * HDIM;
    const bf16* Vb = V + (size_t)bh * S_LEN * HDIM;

    __shared__ float Qs[16][HDIM];
    __shared__ float Ss[16][S_LEN + 4];
    __shared__ float wsum[S_LEN];

    int tid = threadIdx.x;
    for (int t = tid; t < S_LEN; t += 256) wsum[t] = 0.f;
    const float SC = 0.08838834764831845f;   // 1/sqrt(128)

    for (int rb = 0; rb < 32; rb++) {
        __syncthreads();
        for (int e = tid; e < 16 * HDIM; e += 256) {
            int rr = e >> 7, ee = e & 127;
            Qs[rr][ee] = __bfloat162float(Qb[(size_t)(rb * 16 + rr) * HDIM + ee]);
        }
        __syncthreads();
        // thread owns columns t = tid and tid+256
        float acc0[16], acc1[16];
#pragma unroll
        for (int r = 0; r < 16; r++) { acc0[r] = 0.f; acc1[r] = 0.f; }
        const bf16* k0p = Kb + (size_t)tid * HDIM;
        const bf16* k1p = Kb + (size_t)(tid + 256) * HDIM;
        for (int k = 0; k < HDIM; k += 4) {
            short4 r0 = *(const short4*)(k0p + k);
            short4 r1 = *(const short4*)(k1p + k);
            float k0x = __bfloat162float(*(const bf16*)&r0.x);
            float k0y = __bfloat162float(*(const bf16*)&r0.y);
            float k0z = __bfloat162float(*(const bf16*)&r0.z);
            float k0w = __bfloat162float(*(const bf16*)&r0.w);
            float k1x = __bfloat162float(*(const bf16*)&r1.x);
            float k1y = __bfloat162float(*(const bf16*)&r1.y);
            float k1z = __bfloat162float(*(const bf16*)&r1.z);
            float k1w = __bfloat162float(*(const bf16*)&r1.w);
#pragma unroll
            for (int r = 0; r < 16; r++) {
                float4 q = *(const float4*)&Qs[r][k];
                acc0[r] += q.x * k0x + q.y * k0y + q.z * k0z + q.w * k0w;
                acc1[r] += q.x * k1x + q.y * k1y + q.z * k1z + q.w * k1w;
            }
        }
#pragma unroll
        for (int r = 0; r < 16; r++) {
            Ss[r][tid] = acc0[r];
            Ss[r][tid + 256] = acc1[r];
        }
        __syncthreads();
        // softmax each of 16 rows; 16 lanes per row
        {
            int r = tid >> 4, l = tid & 15;
            float m = -1e30f;
            for (int t = l; t < S_LEN; t += 16) m = fmaxf(m, Ss[r][t]);
#pragma unroll
            for (int o = 1; o < 16; o <<= 1) m = fmaxf(m, __shfl_xor(m, o));
            float sum = 0.f;
            for (int t = l; t < S_LEN; t += 16) {
                float p = expf((Ss[r][t] - m) * SC);
                Ss[r][t] = p;
                sum += p;
            }
#pragma unroll
            for (int o = 1; o < 16; o <<= 1) sum += __shfl_xor(sum, o);
            float inv = 1.f / sum;
            for (int t = l; t < S_LEN; t += 16) Ss[r][t] *= inv;
        }
        __syncthreads();
        for (int t = tid; t < S_LEN; t += 256) {
            float s = 0.f;
#pragma unroll
            for (int rr = 0; rr < 16; rr++) s += Ss[rr][t];
            wsum[t] += s;
        }
    }
    __syncthreads();

    if (tid < HDIM) {
        float a = 0.f;
        for (int t = 0; t < S_LEN; t++)
            a += wsum[t] * __bfloat162float(Vb[(size_t)t * HDIM + tid]);
        pooled[(size_t)b * 1024 + h * HDIM + tid] = a * (1.0f / S_LEN);
    }
}

// ---------------- final FC ----------------
__global__ void k_fc(const float* __restrict__ pooled, const float* __restrict__ Wfc,
                     const float* __restrict__ bfc, float* __restrict__ out)
{
    int j = threadIdx.x;
    if (j < 96) {
        int b = j / 3, o = j - b * 3;
        float a = bfc[o];
        for (int k = 0; k < 1024; k++)
            a += pooled[(size_t)b * 1024 + k] * Wfc[(size_t)o * 1024 + k];
        out[j] = a;
    }
}

// ---------------- launch ----------------
extern "C" void kernel_launch(void* const* d_in, const int* in_sizes, int n_in,
                              void* d_out, int out_size, void* d_ws, size_t ws_size,
                              hipStream_t stream)
{
    const int*   x     = (const int*)d_in[0];
    const float* emb   = (const float*)d_in[1];
    const float* Wih0f = (const float*)d_in[2];
    const float* Whh0f = (const float*)d_in[3];
    const float* bih0f = (const float*)d_in[4];
    const float* bhh0f = (const float*)d_in[5];
    const float* Wih0b = (const float*)d_in[6];
    const float* Whh0b = (const float*)d_in[7];
    const float* bih0b = (const float*)d_in[8];
    const float* bhh0b = (const float*)d_in[9];
    const float* Wih1f = (const float*)d_in[10];
    const float* Whh1f = (const float*)d_in[11];
    const float* bih1f = (const float*)d_in[12];
    const float* bhh1f = (const float*)d_in[13];
    const float* Wih1b = (const float*)d_in[14];
    const float* Whh1b = (const float*)d_in[15];
    const float* bih1b = (const float*)d_in[16];
    const float* bhh1b = (const float*)d_in[17];
    const float* Wq    = (const float*)d_in[18];
    const float* bq    = (const float*)d_in[19];
    const float* Wk    = (const float*)d_in[20];
    const float* bk    = (const float*)d_in[21];
    const float* Wv    = (const float*)d_in[22];
    const float* bv    = (const float*)d_in[23];
    const float* Wfc   = (const float*)d_in[24];
    const float* bfc   = (const float*)d_in[25];

    float* ws     = (float*)d_ws;
    float* xgc    = ws + OFF_XGC;
    float* hcat0  = ws + OFF_HCAT0;
    float* hcat1  = ws + OFF_HCAT1;
    float* h0     = ws + OFF_H0;
    float* Wp     = ws + OFF_WP;
    float* pb     = ws + OFF_PB;
    float* cT     = ws + OFF_CT;
    float* hT     = ws + OFF_HT;
    float* pooled = ws + OFF_POOL;
    bf16*  Qbf    = (bf16*)ws;                 // aliases xgc+hcat0 (dead by then)
    bf16*  Kbf    = Qbf + 16777216ull;
    bf16*  Vbf    = Qbf + 33554432ull;

    dim3 blk(256);

    k_embed<<<BATCH * S_LEN, 128, 0, stream>>>(x, emb, h0);
    k_pack<<<12288, 256, 0, stream>>>(Wq, Wk, Wv, bq, bk, bv, Wp, pb);

    // ---- layer 0 ----
    for (int c = 0; c < NCH; c++) {
        k_xgc<<<dim3(16, 16, 2), blk, 0, stream>>>(h0, DIM, Wih0f, Wih0b,
            bih0f, bhh0f, bih0b, bhh0b, xgc, DIM, c * CH);
        for (int i = 0; i < CH; i++)
            k_step<<<256, blk, 0, stream>>>(xgc, Whh0f, Whh0b, hT, cT, hcat0, c * CH + i);
    }
    // ---- layer 1 ----
    for (int c = 0; c < NCH; c++) {
        k_xgc<<<dim3(16, 16, 2), blk, 0, stream>>>(hcat0, 1024, Wih1f, Wih1b,
            bih1f, bhh1f, bih1b, bhh1b, xgc, 1024, c * CH);
        for (int i = 0; i < CH; i++)
            k_step<<<256, blk, 0, stream>>>(xgc, Whh1f, Whh1b, hT, cT, hcat1, c * CH + i);
    }

    // ---- attention ----
    k_qkv<<<dim3(24, 128), blk, 0, stream>>>(hcat1, Wp, pb, Qbf);
    k_attn<<<256, blk, 0, stream>>>(Qbf, Kbf, Vbf, pooled);
    k_fc<<<1, 128, 0, stream>>>(pooled, Wfc, bfc, (float*)d_out);
}